// Round 5
// baseline (94.286 us; speedup 1.0000x reference)
//
#include <hip/hip_runtime.h>

// ---------------------------------------------------------------------------
// cross_entropy_with_hnm_for_one_class_detection
//
// 3 scales: softmax-CE with hard-negative mining (k-th order statistic of
// neg_prob over N=B*H*W) + masked bbox MSE. Output: 3 floats.
//
// R4 bottleneck: hipMemsetAsync -> rocclr fillBuffer dispatch at 39us/replay.
// R5: own k_zero kernel; per-bin CE sums in pass1 (monotone linear binning
// => bins < sel_bin are all <= thr) kill the k_negce full re-scan; select
// kernel fuses the final output computation. 5 launches total.
// ---------------------------------------------------------------------------

namespace {
constexpr int BATCH = 32;
constexpr int HW0 = 25600, HW1 = 6400, HW2 = 1600;
constexpr int N0 = BATCH * HW0;  // 819200
constexpr int N1 = BATCH * HW1;  // 204800
constexpr int N2 = BATCH * HW2;  // 51200

constexpr int LBINS = 4096;
constexpr int CAP = 8192;  // candidate list capacity per scale

// one float4 per thread covers each scale exactly
constexpr int B0 = 800, B1 = 200, B2 = 50;
constexpr int NBLK = B0 + B1 + B2;  // 1050

struct ScaleScal {
  unsigned int pos_cnt, neg_cnt, sel_bin, sel_rank, cand_cnt;
  unsigned int pad0, pad1, pad2;
  double sum_pos_ce, sum_diff2, ce_below, pad3;
};  // 64 bytes

struct P1 {
  double posce, diff2;
  unsigned int pcnt, ncnt;
  unsigned long long pad;
};  // 32 bytes

__device__ inline void scale_of(int blk, int& s, int& rel, int& N, int& base) {
  if (blk < B0) {
    s = 0; rel = blk; N = N0; base = 0;
  } else if (blk < B0 + B1) {
    s = 1; rel = blk - B0; N = N1; base = N0;
  } else {
    s = 2; rel = blk - B0 - B1; N = N2; base = N0 + N1;
  }
}

__device__ inline unsigned int lin_bin(float v) {
  unsigned int b = (unsigned int)(v * 4096.0f);
  return b > 4095u ? 4095u : b;
}
}  // namespace

// ---------------- pass 0: zero control region (hist, histce, scal) ----------
__global__ __launch_bounds__(256) void k_zero(uint4* __restrict__ p, int n4) {
  for (int i = blockIdx.x * 256 + threadIdx.x; i < n4; i += gridDim.x * 256)
    p[i] = make_uint4(0u, 0u, 0u, 0u);
}

// ---------------- pass 1: softmax, counts, pos-CE, bbox, hist + CE hist -----
template <int HW, int N>
__device__ void pass1_body(int rel, const float* __restrict__ sc,
                           const float* __restrict__ bb,
                           const float* __restrict__ gl,
                           unsigned int* __restrict__ hist,
                           float* __restrict__ histce,
                           float* __restrict__ npv,
                           unsigned int* __restrict__ lh,
                           float* __restrict__ lhce, P1* __restrict__ p1) {
  const int tid = threadIdx.x;
  for (int i = tid; i < LBINS; i += 256) { lh[i] = 0; lhce[i] = 0.0f; }
  __syncthreads();

  double posce = 0.0, diff2 = 0.0;
  unsigned int pcnt = 0, ncnt = 0;
  const int q = (rel * 256 + tid) * 4;
  {
    const int b = q / HW;
    const int hw = q - b * HW;
    const float4 s0v = *(const float4*)(sc + (size_t)b * 2 * HW + hw);
    const float4 s1v = *(const float4*)(sc + (size_t)b * 2 * HW + HW + hw);
    const float4 l0v = *(const float4*)(gl + (size_t)b * 6 * HW + hw);
    const float4 l1v = *(const float4*)(gl + (size_t)b * 6 * HW + HW + hw);
    const float s0a[4] = {s0v.x, s0v.y, s0v.z, s0v.w};
    const float s1a[4] = {s1v.x, s1v.y, s1v.z, s1v.w};
    const float l0a[4] = {l0v.x, l0v.y, l0v.z, l0v.w};
    const float l1a[4] = {l1v.x, l1v.y, l1v.z, l1v.w};
    float np[4];
#pragma unroll
    for (int j = 0; j < 4; ++j) {
      const float d = s1a[j] - s0a[j];
      const float t = expf(-fabsf(d));
      const float l1p = log1pf(t);  // = lse after max-sub
      const bool pos = l0a[j] > 0.5f;
      const bool neg = l1a[j] > 0.5f;
      const float sm1 = ((d >= 0.0f) ? 1.0f : t) / (1.0f + t);
      const float v = neg ? sm1 : 0.0f;
      np[j] = v;
      const unsigned int bin = lin_bin(v);
      atomicAdd(&lh[bin], 1u);
      if (neg) {
        ncnt++;
        // ce = -ls1 = l1p - min(d,0)
        const float ce = l1p - ((d >= 0.0f) ? 0.0f : d);
        atomicAdd(&lhce[bin], ce);
      }
      if (pos) {
        pcnt++;
        const float ls0 = ((d > 0.0f) ? -d : 0.0f) - l1p;
        posce += (double)(-l0a[j] * ls0);
        const float* glp = gl + (size_t)b * 6 * HW + hw + j;
        const float* bbp = bb + (size_t)b * 4 * HW + hw + j;
        float acc = 0.0f;
#pragma unroll
        for (int c = 0; c < 4; ++c) {
          const float dd = glp[(2 + c) * HW] - bbp[c * HW];
          acc += dd * dd;
        }
        diff2 += (double)acc;
      }
    }
    *(float4*)(npv + q) = make_float4(np[0], np[1], np[2], np[3]);
  }
  __syncthreads();
  for (int i = tid; i < LBINS; i += 256) {
    const unsigned int c = lh[i];
    if (c) atomicAdd(&hist[i], c);  // u32 HW atomic
    const float e = lhce[i];
    if (e != 0.0f) atomicAdd(&histce[i], e);  // f32 HW atomic
  }

  __shared__ double sd[256];
  __shared__ unsigned int su[256];
  sd[tid] = posce;
  su[tid] = pcnt;
  __syncthreads();
  for (int o = 128; o > 0; o >>= 1) {
    if (tid < o) { sd[tid] += sd[tid + o]; su[tid] += su[tid + o]; }
    __syncthreads();
  }
  if (tid == 0) { p1->posce = sd[0]; p1->pcnt = su[0]; }
  __syncthreads();
  sd[tid] = diff2;
  su[tid] = ncnt;
  __syncthreads();
  for (int o = 128; o > 0; o >>= 1) {
    if (tid < o) { sd[tid] += sd[tid + o]; su[tid] += su[tid + o]; }
    __syncthreads();
  }
  if (tid == 0) { p1->diff2 = sd[0]; p1->ncnt = su[0]; }
}

__global__ __launch_bounds__(256) void k_pass1(
    const float* sc0, const float* bb0, const float* gl0,
    const float* sc1, const float* bb1, const float* gl1,
    const float* sc2, const float* bb2, const float* gl2,
    unsigned int* hist, float* histce, float* npv, P1* part1) {
  __shared__ unsigned int lh[LBINS];
  __shared__ float lhce[LBINS];
  int s, rel, N, base;
  scale_of(blockIdx.x, s, rel, N, base);
  P1* p1 = part1 + blockIdx.x;
  if (s == 0)
    pass1_body<HW0, N0>(rel, sc0, bb0, gl0, hist, histce, npv, lh, lhce, p1);
  else if (s == 1)
    pass1_body<HW1, N1>(rel, sc1, bb1, gl1, hist + LBINS, histce + LBINS,
                        npv + N0, lh, lhce, p1);
  else
    pass1_body<HW2, N2>(rel, sc2, bb2, gl2, hist + 2 * LBINS,
                        histce + 2 * LBINS, npv + N0 + N1, lh, lhce, p1);
}

// ------- pass 2: reduce partials; scan hist + CE hist -> sel bin, ce_below --
__global__ __launch_bounds__(256) void k_mid(const P1* __restrict__ part1,
                                             const unsigned int* __restrict__ hist,
                                             const float* __restrict__ histce,
                                             ScaleScal* scal) {
  const int s = blockIdx.x;
  const int lo = (s == 0) ? 0 : (s == 1) ? B0 : B0 + B1;
  const int hi = (s == 0) ? B0 : (s == 1) ? B0 + B1 : NBLK;
  const int tid = threadIdx.x;
  __shared__ double sda[256], sdb[256];
  __shared__ unsigned int sua[256], sub[256];
  {
    double a = 0, b = 0;
    unsigned int c = 0, d = 0;
    for (int i = lo + tid; i < hi; i += 256) {
      a += part1[i].posce; b += part1[i].diff2;
      c += part1[i].pcnt;  d += part1[i].ncnt;
    }
    sda[tid] = a; sdb[tid] = b; sua[tid] = c; sub[tid] = d;
  }
  __syncthreads();
  for (int o = 128; o > 0; o >>= 1) {
    if (tid < o) {
      sda[tid] += sda[tid + o]; sdb[tid] += sdb[tid + o];
      sua[tid] += sua[tid + o]; sub[tid] += sub[tid + o];
    }
    __syncthreads();
  }
  __shared__ unsigned int kk;
  if (tid == 0) {
    scal[s].sum_pos_ce = sda[0];
    scal[s].sum_diff2 = sdb[0];
    scal[s].pos_cnt = sua[0];
    scal[s].neg_cnt = sub[0];
    const unsigned long long k10 = 10ull * (unsigned long long)sua[0];
    kk = (k10 < (unsigned long long)sub[0]) ? (unsigned int)k10 : sub[0];
  }
  __syncthreads();

  // dual scan: counts (exact rank) + CE (f64 accumulation of f32 bins)
  __shared__ unsigned int ldc[LBINS];
  __shared__ float lde[LBINS];
  const unsigned int* hc = hist + s * LBINS;
  const float* he = histce + s * LBINS;
  for (int i = tid; i < LBINS; i += 256) { ldc[i] = hc[i]; lde[i] = he[i]; }
  __syncthreads();
  __shared__ unsigned int partC[256];
  __shared__ double partE[256];
  constexpr int per = LBINS / 256;
  unsigned int ownC = 0;
  double ownE = 0.0;
#pragma unroll
  for (int i = 0; i < per; ++i) {
    ownC += ldc[tid * per + i];
    ownE += (double)lde[tid * per + i];
  }
  partC[tid] = ownC;
  partE[tid] = ownE;
  __syncthreads();
  for (int o = 1; o < 256; o <<= 1) {  // inclusive Hillis-Steele
    const unsigned int aC = (tid >= o) ? partC[tid - o] : 0u;
    const double aE = (tid >= o) ? partE[tid - o] : 0.0;
    __syncthreads();
    partC[tid] += aC;
    partE[tid] += aE;
    __syncthreads();
  }
  const unsigned int k = kk;
  const unsigned int inclC = partC[tid];
  const unsigned int exclC = inclC - ownC;
  if (ownC && k >= exclC && k < inclC) {  // unique winner
    unsigned int run = exclC;
    double ceRun = partE[tid] - ownE;
#pragma unroll
    for (int i = 0; i < per; ++i) {
      const unsigned int c = ldc[tid * per + i];
      if (run + c > k) {
        scal[s].sel_bin = (unsigned int)(tid * per + i);
        scal[s].sel_rank = k - run;
        scal[s].ce_below = ceRun;
        break;
      }
      run += c;
      ceRun += (double)lde[tid * per + i];
    }
  }
}

// ---------------- pass 3: gather candidates of selected linear bin ----------
__global__ __launch_bounds__(256) void k_cand(const float* __restrict__ npv,
                                              ScaleScal* scal,
                                              unsigned int* __restrict__ cand) {
  int s, rel, N, base;
  scale_of(blockIdx.x, s, rel, N, base);
  const unsigned int bsel = scal[s].sel_bin;
  unsigned int* lst = cand + s * CAP;
  const int q = (rel * 256 + threadIdx.x) * 4;
  const float4 v4 = *(const float4*)(npv + base + q);
  const float va[4] = {v4.x, v4.y, v4.z, v4.w};
#pragma unroll
  for (int j = 0; j < 4; ++j) {
    if (lin_bin(va[j]) == bsel) {
      const unsigned int slot = atomicAdd(&scal[s].cand_cnt, 1u);
      if (slot < CAP) lst[slot] = __float_as_uint(va[j]);
    }
  }
}

// ------- pass 4: radix select over candidates; in-bin CE; final outputs -----
__global__ __launch_bounds__(256) void k_select(
    const ScaleScal* __restrict__ scal, const unsigned int* __restrict__ cand,
    float* __restrict__ out) {
  const int s = blockIdx.x;
  const int tid = threadIdx.x;
  __shared__ unsigned int vals[CAP];  // 32 KiB
  __shared__ unsigned int hist[256];
  __shared__ unsigned int sh_prefix, sh_rank;
  const unsigned int n = min(scal[s].cand_cnt, (unsigned int)CAP);
  if (tid == 0) {
    sh_prefix = 0;
    sh_rank = scal[s].sel_rank;
  }
  for (unsigned int i = tid; i < n; i += 256) vals[i] = cand[s * CAP + i];
  __syncthreads();
#pragma unroll
  for (int round = 0; round < 4; ++round) {
    const int shift = 24 - 8 * round;
    hist[tid] = 0;
    __syncthreads();
    const unsigned int pref = sh_prefix;
    for (unsigned int i = tid; i < n; i += 256) {
      const unsigned int v = vals[i];
      const bool match =
          (round == 0) || ((v >> (shift + 8)) == (pref >> (shift + 8)));
      if (match) atomicAdd(&hist[(v >> shift) & 255u], 1u);
    }
    __syncthreads();
    if (tid == 0) {
      unsigned int k = sh_rank, run = 0, sel = 255;
      for (int bkt = 0; bkt < 256; ++bkt) {
        const unsigned int c = hist[bkt];
        if (run + c > k) { sel = (unsigned int)bkt; break; }
        run += c;
      }
      sh_prefix = pref | (sel << shift);
      sh_rank = k - run;
    }
    __syncthreads();
  }
  const float thr = __uint_as_float(sh_prefix);

  // in-bin CE: candidates with 0 < v <= thr (v==0 => pos element => ce 0)
  double acc = 0.0;
  for (unsigned int i = tid; i < n; i += 256) {
    const float v = __uint_as_float(vals[i]);
    if (v > 0.0f && v <= thr) acc += (double)(-logf(v));
  }
  __shared__ double sd[256];
  sd[tid] = acc;
  __syncthreads();
  for (int o = 128; o > 0; o >>= 1) {
    if (tid < o) sd[tid] += sd[tid + o];
    __syncthreads();
  }
  if (tid == 0) {
    const ScaleScal& ss = scal[s];
    const double Ns = (s == 0) ? (double)N0 : (s == 1) ? (double)N1 : (double)N2;
    const double W = (s == 0) ? 160.0 : (s == 1) ? 80.0 : 40.0;
    const double ls = (ss.sum_pos_ce + ss.ce_below + sd[0]) / (2.0 * Ns);
    const double lb = (ss.sum_diff2 / W) / (4.0 * (double)ss.pos_cnt);
    out[s] = (float)(ls + lb);
  }
}

extern "C" void kernel_launch(void* const* d_in, const int* in_sizes, int n_in,
                              void* d_out, int out_size, void* d_ws,
                              size_t ws_size, hipStream_t stream) {
  const float* sc0 = (const float*)d_in[0];
  const float* bb0 = (const float*)d_in[1];
  const float* gl0 = (const float*)d_in[3];
  const float* sc1 = (const float*)d_in[4];
  const float* bb1 = (const float*)d_in[5];
  const float* gl1 = (const float*)d_in[7];
  const float* sc2 = (const float*)d_in[8];
  const float* bb2 = (const float*)d_in[9];
  const float* gl2 = (const float*)d_in[11];

  char* ws = (char*)d_ws;
  unsigned int* hist = (unsigned int*)ws;            // 3*4096 u32 = 48 KiB
  float* histce = (float*)(hist + 3 * LBINS);        // 3*4096 f32 = 48 KiB
  ScaleScal* scal = (ScaleScal*)(histce + 3 * LBINS);
  size_t zbytes = (size_t)3 * LBINS * 4 * 2 + 3 * sizeof(ScaleScal);
  zbytes = (zbytes + 255) & ~(size_t)255;
  P1* part1 = (P1*)(ws + zbytes);                    // NBLK * 32 B
  size_t off = zbytes + (size_t)NBLK * sizeof(P1);
  off = (off + 255) & ~(size_t)255;
  unsigned int* cand = (unsigned int*)(ws + off);    // 3*CAP u32
  off += (size_t)3 * CAP * 4;
  off = (off + 255) & ~(size_t)255;
  float* npv = (float*)(ws + off);                   // NT floats

  const dim3 blk(256);
  k_zero<<<dim3(32), blk, 0, stream>>>((uint4*)d_ws, (int)(zbytes >> 4));
  k_pass1<<<dim3(NBLK), blk, 0, stream>>>(sc0, bb0, gl0, sc1, bb1, gl1, sc2,
                                          bb2, gl2, hist, histce, npv, part1);
  k_mid<<<dim3(3), blk, 0, stream>>>(part1, hist, histce, scal);
  k_cand<<<dim3(NBLK), blk, 0, stream>>>(npv, scal, cand);
  k_select<<<dim3(3), blk, 0, stream>>>(scal, cand, (float*)d_out);
}